// Round 11
// baseline (81.197 us; speedup 1.0000x reference)
//
#include <hip/hip_runtime.h>
#include <hip/hip_bf16.h>

#define HIDDEN 1024
#define HEADS  2560

// GEMM geometry: 256x128 tile, BK=32, grid = (8192/256)*(2560/128) = 32*20 = 640.
// 8 waves (4M x 2N), per-wave 64x64 = acc[4][4] (64 VGPR): LDS reads/output
// = 64B vs R7's 87.5B (-27%). LDS: 2 * (16384+8192) = 48KB -> 2 blocks/CU.
#define BM 256
#define BN 128
#define BK 32
#define NT (HIDDEN / BK)        // 32 K-tiles
#define ABYT (BM * BK * 2)      // 16384
#define BBYT (BN * BK * 2)      // 8192
#define BUFSZ (ABYT + BBYT)     // 24576

typedef float  f32x4  __attribute__((ext_vector_type(4)));
typedef __bf16 bf16x8 __attribute__((ext_vector_type(8)));
typedef __bf16 bf16x4 __attribute__((ext_vector_type(4)));

__device__ __forceinline__ void gload_lds16(const void* g, void* l) {
    __builtin_amdgcn_global_load_lds(
        (const __attribute__((address_space(1))) unsigned int*)g,
        (__attribute__((address_space(3))) unsigned int*)l, 16, 0, 0);
}
// 64B-row swizzle: logical byte x (row = x>>6) lives at x ^ ((row&3)<<4).
// Involution; bits >=6 unchanged. A wave's fragment b128 read (16 rows x 4
// chunks) covers a permuted contiguous 1KB block -> conflict-free.
__device__ __forceinline__ unsigned swz(unsigned x) {
    return x ^ (((x >> 6) & 3u) << 4);
}

// ---------------------------------------------------------------------------
// Fused pass 1: blocks [0,640) transpose W f32[K][N] -> Wt bf16[N][K];
//               blocks [640,...) convert x f32 -> bf16.
// ---------------------------------------------------------------------------
__global__ __launch_bounds__(256)
void cvt_all(const float* __restrict__ x, const float* __restrict__ W,
             __bf16* __restrict__ xc, __bf16* __restrict__ Wt, int n8)
{
    if (blockIdx.x < 640) {
        __shared__ __bf16 tile[64][72];
        const int t  = threadIdx.x;
        const int n0 = (blockIdx.x % 40) * 64;
        const int k0 = (blockIdx.x / 40) * 64;

        #pragma unroll
        for (int i = 0; i < 4; ++i) {
            const int k    = (t >> 4) + i * 16;
            const int col4 = (t & 15) * 4;
            const float4 v = *reinterpret_cast<const float4*>(
                W + (size_t)(k0 + k) * HEADS + n0 + col4);
            bf16x4 h;
            h[0] = (__bf16)v.x; h[1] = (__bf16)v.y; h[2] = (__bf16)v.z; h[3] = (__bf16)v.w;
            *reinterpret_cast<bf16x4*>(&tile[k][col4]) = h;
        }
        __syncthreads();
        #pragma unroll
        for (int i = 0; i < 4; ++i) {
            const int n  = (t >> 4) + i * 16;
            const int k4 = (t & 15) * 4;
            bf16x4 h;
            h[0] = tile[k4 + 0][n]; h[1] = tile[k4 + 1][n];
            h[2] = tile[k4 + 2][n]; h[3] = tile[k4 + 3][n];
            *reinterpret_cast<bf16x4*>(Wt + (size_t)(n0 + n) * HIDDEN + k0 + k4) = h;
        }
    } else {
        int idx    = (blockIdx.x - 640) * blockDim.x + threadIdx.x;
        int stride = (gridDim.x - 640) * blockDim.x;
        for (int i = idx; i < n8; i += stride) {
            const float4 a = *reinterpret_cast<const float4*>(x + (size_t)i * 8);
            const float4 b = *reinterpret_cast<const float4*>(x + (size_t)i * 8 + 4);
            bf16x8 h;
            h[0] = (__bf16)a.x; h[1] = (__bf16)a.y; h[2] = (__bf16)a.z; h[3] = (__bf16)a.w;
            h[4] = (__bf16)b.x; h[5] = (__bf16)b.y; h[6] = (__bf16)b.z; h[7] = (__bf16)b.w;
            *reinterpret_cast<bf16x8*>(xc + (size_t)i * 8) = h;
        }
    }
}

// ---------------------------------------------------------------------------
// Pass 2: R7 delockstep schedule on square per-wave tiles. Per K-tile:
// {issue 3 gload_lds for k+1 | 8 ds_read_b128 + 16 MFMA (compiler-scheduled)
// | vmcnt(0) covered by full tile | one s_barrier}. No setprio (R10: null).
// XCD map: XCD x processes g in [80x,80x+80) -> bx in [4x,4x+4): 2MB A-slab
// L2-resident; B panels (5MB total) L3-resident.
// ---------------------------------------------------------------------------
__global__ __launch_bounds__(512, 4)
void gemm_sq(const __bf16* __restrict__ A, const __bf16* __restrict__ Bt,
             const float* __restrict__ bias, float* __restrict__ out)
{
    __shared__ char lds[2 * BUFSZ];   // 48 KB

    const int t    = threadIdx.x;
    const int lane = t & 63;
    const int w    = t >> 6;      // 0..7
    const int wr   = w & 3;       // 0..3 : 64-row slab
    const int wc   = w >> 2;      // 0..1 : 64-col slab
    const int lhi  = lane >> 4;   // 0..3
    const int llo  = lane & 15;   // 0..15

    // XCD-grouped bijective remap (640 = 8 * 80)
    const int g   = (blockIdx.x & 7) * 80 + (blockIdx.x >> 3);
    const int bx  = g / 20;
    const int by  = g % 20;
    const int bm0 = bx * BM;
    const int bn0 = by * BN;

    // ---- staging descriptors: linear LDS dest d, pre-swizzled global source.
    // d = t*16 in [0,8192): row = d>>6, in-row col = (d&63) ^ ((row&3)<<4).
    // A sweep 2 (d+8192): row += 128, row&3 unchanged -> src advance 262144 B.
    const unsigned d0 = (unsigned)(t * 16);
    const unsigned r0 = d0 >> 6;
    const unsigned c0 = (d0 & 63) ^ ((r0 & 3u) << 4);
    const char* asrc0 = (const char*)A  + (size_t)(bm0 + r0) * (HIDDEN * 2) + c0;
    const char* bsrc0 = (const char*)Bt + (size_t)(bn0 + r0) * (HIDDEN * 2) + c0;
    char* adst0 = (char*)lds + d0;           // A region [0, 16384), rows 0..255
    char* bdst0 = (char*)lds + ABYT + d0;    // B region [16384, 24576), rows 0..127

    // ---- fragment read offsets. klo < 64, rowbase multiple of 64 -> no carry
    // into row bits (R6 lesson). row&3 == llo&3 for both A and B fragments.
    const unsigned klo  = ((unsigned)(lhi * 16)) ^ ((unsigned)((llo & 3) << 4));
    const unsigned rowA = (unsigned)((wr * 64 + llo) * 64);
    const unsigned rowB = (unsigned)ABYT + (unsigned)((wc * 64 + llo) * 64);

    f32x4 acc[4][4];
    #pragma unroll
    for (int m = 0; m < 4; ++m)
        #pragma unroll
        for (int n = 0; n < 4; ++n)
            acc[m][n] = f32x4{0.f, 0.f, 0.f, 0.f};

    // ---- prologue: stage T0 -> buf0 (3 gload_lds / thread)
    gload_lds16(asrc0,          adst0);
    gload_lds16(asrc0 + 262144, adst0 + 8192);
    gload_lds16(bsrc0,          bdst0);
    asm volatile("s_waitcnt vmcnt(0)" ::: "memory");
    __builtin_amdgcn_s_barrier();

    for (int k = 0; k < NT; ++k) {
        const char* buf  = lds + (k & 1) * BUFSZ;
        const unsigned nb = (unsigned)(((k + 1) & 1) * BUFSZ);
        const int   koff = (k + 1) * 64;   // 32 bf16 per K-tile = 64 B

        // ---- early issue: stage tile k+1 (a full tile of latency cover)
        if (k + 1 < NT) {
            gload_lds16(asrc0 + koff,          adst0 + nb);
            gload_lds16(asrc0 + koff + 262144, adst0 + nb + 8192);
            gload_lds16(bsrc0 + koff,          bdst0 + nb);
        }

        // ---- compute: 8 ds_read_b128 + 16 MFMA, compiler-scheduled
        bf16x8 af[4], bfr[4];
        #pragma unroll
        for (int m = 0; m < 4; ++m)
            af[m]  = *(const bf16x8*)(buf + rowA + m * 1024 + klo);
        #pragma unroll
        for (int n = 0; n < 4; ++n)
            bfr[n] = *(const bf16x8*)(buf + rowB + n * 1024 + klo);
        #pragma unroll
        for (int m = 0; m < 4; ++m)
            #pragma unroll
            for (int n = 0; n < 4; ++n)
                acc[m][n] = __builtin_amdgcn_mfma_f32_16x16x32_bf16(
                    af[m], bfr[n], acc[m][n], 0, 0, 0);

        // ---- tile boundary: staged loads had a full tile to land
        asm volatile("s_waitcnt vmcnt(0)" ::: "memory");
        __builtin_amdgcn_s_barrier();
    }

    // ---- epilogue: bias + sigmoid; C/D: col = lane&15, row = (lane>>4)*4+reg
    #pragma unroll
    for (int n = 0; n < 4; ++n) {
        const int col  = bn0 + wc * 64 + n * 16 + llo;
        const float bv = bias[col];
        #pragma unroll
        for (int m = 0; m < 4; ++m) {
            const int row0 = bm0 + wr * 64 + m * 16 + lhi * 4;
            #pragma unroll
            for (int r = 0; r < 4; ++r) {
                const float z = acc[m][n][r] + bv;
                out[(size_t)(row0 + r) * HEADS + col] = __fdividef(1.0f, 1.0f + __expf(-z));
            }
        }
    }
}

// ---------------------------------------------------------------------------
// Fallback (R1 fused kernel) if workspace is too small.
// ---------------------------------------------------------------------------
#define FBM 128
#define FBN 128
#define FBK 32
#define FLDK 40

__global__ __launch_bounds__(256)
void lch_gemm(const float* __restrict__ x, const float* __restrict__ W,
              const float* __restrict__ b, float* __restrict__ out)
{
    __shared__ __bf16 As[FBM][FLDK];
    __shared__ __bf16 Bs[FBN][FLDK];

    const int t   = threadIdx.x;
    const int bm0 = blockIdx.x * FBM;
    const int bn0 = blockIdx.y * FBN;
    const int lane = t & 63;
    const int wid  = t >> 6;
    const int wr   = wid >> 1;
    const int wc   = wid & 1;
    const int lhi  = lane >> 4;
    const int llo  = lane & 15;

    f32x4 acc[4][4];
    #pragma unroll
    for (int i = 0; i < 4; ++i)
        #pragma unroll
        for (int j = 0; j < 4; ++j)
            acc[i][j] = f32x4{0.f, 0.f, 0.f, 0.f};

    const int bn_col  = t & 127;
    const int bk_base = (t >> 7) * 16;

    for (int k0 = 0; k0 < HIDDEN; k0 += FBK) {
        #pragma unroll
        for (int i = 0; i < 4; ++i) {
            const int f   = t + i * 256;
            const int row = f >> 3;
            const int c4  = (f & 7) * 4;
            const float4 v = *reinterpret_cast<const float4*>(
                x + (size_t)(bm0 + row) * HIDDEN + k0 + c4);
            bf16x4 h;
            h[0] = (__bf16)v.x; h[1] = (__bf16)v.y;
            h[2] = (__bf16)v.z; h[3] = (__bf16)v.w;
            *reinterpret_cast<bf16x4*>(&As[row][c4]) = h;
        }
        {
            const float* wp = W + (size_t)(k0 + bk_base) * HEADS + bn0 + bn_col;
            bf16x8 h0, h1;
            #pragma unroll
            for (int i = 0; i < 8; ++i) h0[i] = (__bf16)wp[(size_t)i * HEADS];
            #pragma unroll
            for (int i = 0; i < 8; ++i) h1[i] = (__bf16)wp[(size_t)(i + 8) * HEADS];
            *reinterpret_cast<bf16x8*>(&Bs[bn_col][bk_base])     = h0;
            *reinterpret_cast<bf16x8*>(&Bs[bn_col][bk_base + 8]) = h1;
        }
        __syncthreads();

        bf16x8 af[4], bfr[4];
        #pragma unroll
        for (int i = 0; i < 4; ++i)
            af[i] = *reinterpret_cast<const bf16x8*>(&As[wr * 64 + i * 16 + llo][lhi * 8]);
        #pragma unroll
        for (int j = 0; j < 4; ++j)
            bfr[j] = *reinterpret_cast<const bf16x8*>(&Bs[wc * 64 + j * 16 + llo][lhi * 8]);
        #pragma unroll
        for (int i = 0; i < 4; ++i)
            #pragma unroll
            for (int j = 0; j < 4; ++j)
                acc[i][j] = __builtin_amdgcn_mfma_f32_16x16x32_bf16(
                    af[i], bfr[j], acc[i][j], 0, 0, 0);
        __syncthreads();
    }

    #pragma unroll
    for (int j = 0; j < 4; ++j) {
        const int col  = bn0 + wc * 64 + j * 16 + llo;
        const float bv = b[col];
        #pragma unroll
        for (int i = 0; i < 4; ++i) {
            const int row0 = bm0 + wr * 64 + i * 16 + lhi * 4;
            #pragma unroll
            for (int r = 0; r < 4; ++r) {
                const float z = acc[i][j][r] + bv;
                out[(size_t)(row0 + r) * HEADS + col] = 1.0f / (1.0f + __expf(-z));
            }
        }
    }
}

extern "C" void kernel_launch(void* const* d_in, const int* in_sizes, int n_in,
                              void* d_out, int out_size, void* d_ws, size_t ws_size,
                              hipStream_t stream) {
    const float* x = (const float*)d_in[0];
    const float* W = (const float*)d_in[1];
    const float* b = (const float*)d_in[2];
    float* out     = (float*)d_out;

    const int M = in_sizes[0] / HIDDEN;   // 8192

    const size_t xc_bytes = (size_t)M * HIDDEN * sizeof(__bf16);
    const size_t wt_bytes = (size_t)HEADS * HIDDEN * sizeof(__bf16);

    if (ws_size >= xc_bytes + wt_bytes && (M % BM) == 0) {
        __bf16* xc = (__bf16*)d_ws;
        __bf16* Wt = (__bf16*)((char*)d_ws + xc_bytes);

        cvt_all<<<640 + 2048, 256, 0, stream>>>(x, W, xc, Wt, M * HIDDEN / 8);

        const int nwg = (M / BM) * (HEADS / BN);   // 32 * 20 = 640
        gemm_sq<<<nwg, 512, 0, stream>>>(xc, Wt, b, out);
    } else {
        dim3 grid(M / FBM, HEADS / FBN);
        lch_gemm<<<grid, dim3(256), 0, stream>>>(x, W, b, out);
    }
}

// Round 12
// 70.088 us; speedup vs baseline: 1.1585x; 1.1585x over previous
//
#include <hip/hip_runtime.h>
#include <hip/hip_bf16.h>

#define HIDDEN 1024
#define HEADS  2560

// GEMM geometry: 256x160 tile, BK=32, grid = (8192/256)*(2560/160) = 32*16 = 512
// = 2.0 blocks/CU. 8 waves (4M x 2N), per-wave 64x80 = acc[4][5] (80 VGPR).
// LDS pair-packed: logical row r at physical row r>>1, half (r&1)*64 -> 128B
// physical rows -> the R7-proven ((prow&7)<<4) swizzle (0 conflicts).
// LDS: 2 * (16384 + 10240) = 53248 B -> 2 blocks/CU, 16 waves/CU.
#define BM 256
#define BN 160
#define BK 32
#define NT (HIDDEN / BK)        // 32 K-tiles
#define ABYT (BM * BK * 2)      // 16384
#define BBYT (BN * BK * 2)      // 10240
#define BUFSZ (ABYT + BBYT)     // 26624

typedef float  f32x4  __attribute__((ext_vector_type(4)));
typedef __bf16 bf16x8 __attribute__((ext_vector_type(8)));
typedef __bf16 bf16x4 __attribute__((ext_vector_type(4)));

__device__ __forceinline__ void gload_lds16(const void* g, void* l) {
    __builtin_amdgcn_global_load_lds(
        (const __attribute__((address_space(1))) unsigned int*)g,
        (__attribute__((address_space(3))) unsigned int*)l, 16, 0, 0);
}

// ---------------------------------------------------------------------------
// Fused pass 1: blocks [0,640) transpose W f32[K][N] -> Wt bf16[N][K];
//               blocks [640,...) convert x f32 -> bf16.
// ---------------------------------------------------------------------------
__global__ __launch_bounds__(256)
void cvt_all(const float* __restrict__ x, const float* __restrict__ W,
             __bf16* __restrict__ xc, __bf16* __restrict__ Wt, int n8)
{
    if (blockIdx.x < 640) {
        __shared__ __bf16 tile[64][72];
        const int t  = threadIdx.x;
        const int n0 = (blockIdx.x % 40) * 64;
        const int k0 = (blockIdx.x / 40) * 64;

        #pragma unroll
        for (int i = 0; i < 4; ++i) {
            const int k    = (t >> 4) + i * 16;
            const int col4 = (t & 15) * 4;
            const float4 v = *reinterpret_cast<const float4*>(
                W + (size_t)(k0 + k) * HEADS + n0 + col4);
            bf16x4 h;
            h[0] = (__bf16)v.x; h[1] = (__bf16)v.y; h[2] = (__bf16)v.z; h[3] = (__bf16)v.w;
            *reinterpret_cast<bf16x4*>(&tile[k][col4]) = h;
        }
        __syncthreads();
        #pragma unroll
        for (int i = 0; i < 4; ++i) {
            const int n  = (t >> 4) + i * 16;
            const int k4 = (t & 15) * 4;
            bf16x4 h;
            h[0] = tile[k4 + 0][n]; h[1] = tile[k4 + 1][n];
            h[2] = tile[k4 + 2][n]; h[3] = tile[k4 + 3][n];
            *reinterpret_cast<bf16x4*>(Wt + (size_t)(n0 + n) * HIDDEN + k0 + k4) = h;
        }
    } else {
        int idx    = (blockIdx.x - 640) * blockDim.x + threadIdx.x;
        int stride = (gridDim.x - 640) * blockDim.x;
        for (int i = idx; i < n8; i += stride) {
            const float4 a = *reinterpret_cast<const float4*>(x + (size_t)i * 8);
            const float4 b = *reinterpret_cast<const float4*>(x + (size_t)i * 8 + 4);
            bf16x8 h;
            h[0] = (__bf16)a.x; h[1] = (__bf16)a.y; h[2] = (__bf16)a.z; h[3] = (__bf16)a.w;
            h[4] = (__bf16)b.x; h[5] = (__bf16)b.y; h[6] = (__bf16)b.z; h[7] = (__bf16)b.w;
            *reinterpret_cast<bf16x8*>(xc + (size_t)i * 8) = h;
        }
    }
}

// ---------------------------------------------------------------------------
// Pass 2: pair-packed square-ish wave tiles on the R7 delockstep schedule.
// Per K-tile: {issue 3-4 gload_lds for k+1 | 9 ds_read_b128 + 20 MFMA
// (compiler fine-grained lgkmcnt) | vmcnt(0) covered by full tile | one
// s_barrier}. A fragment read's 64 lanes hit 8 physical rows x all 8 chunks
// each (R7 bank pattern -> 0 conflicts).
// ---------------------------------------------------------------------------
__global__ __launch_bounds__(512, 4)
void gemm_pp(const __bf16* __restrict__ A, const __bf16* __restrict__ Bt,
             const float* __restrict__ bias, float* __restrict__ out)
{
    __shared__ char lds[2 * BUFSZ];   // 53248 B

    const int t    = threadIdx.x;
    const int lane = t & 63;
    const int w    = t >> 6;      // 0..7
    const int wr   = w & 3;       // 0..3 : 64-row slab
    const int wc   = w >> 2;      // 0..1 : 80-col slab
    const int lhi  = lane >> 4;   // 0..3
    const int llo  = lane & 15;   // 0..15

    // XCD-grouped bijective remap (512 = 8 * 64): XCD x -> bx in [4x,4x+4)
    // (4 A-slabs = 2MB, L2-resident), all 16 B-panels stream via L3.
    const int g   = (blockIdx.x & 7) * 64 + (blockIdx.x >> 3);
    const int bx  = g >> 4;
    const int by  = g & 15;
    const int bm0 = bx * BM;
    const int bn0 = by * BN;

    // ---- staging descriptors. LDS physical byte d: prow = d>>7, in-row
    // il_phys = d&127; logical in-row il = il_phys ^ ((prow&7)<<4); logical
    // row lr = (prow<<1) | (il>>6); k-byte c = il&63. Source = row lr, byte c.
    // Sweep advance d+=8192: prow += 64 (prow&7 invariant) -> lr += 128 ->
    // uniform source advance 128*2048 = 262144 B.
    const unsigned dA = (unsigned)(t * 16);
    unsigned prowA = dA >> 7;
    unsigned ilA   = (dA & 127u) ^ ((prowA & 7u) << 4);
    const char* asrc0 = (const char*)A
        + (size_t)(bm0 + (int)((prowA << 1) | (ilA >> 6))) * 2048 + (ilA & 63u);
    const char* bsrc0 = (const char*)Bt
        + (size_t)(bn0 + (int)((prowA << 1) | (ilA >> 6))) * 2048 + (ilA & 63u);
    char* adst0 = (char*)lds + dA;           // A region [0, 16384)
    char* bdst0 = (char*)lds + ABYT + dA;    // B region [16384, 26624)

    const unsigned dBt = 8192u + (unsigned)((t & 127) * 16);  // B tail, t<128
    unsigned prowT = dBt >> 7;
    unsigned ilT   = (dBt & 127u) ^ ((prowT & 7u) << 4);
    const char* bsrct = (const char*)Bt
        + (size_t)(bn0 + (int)((prowT << 1) | (ilT >> 6))) * 2048 + (ilT & 63u);
    char* bdstt = (char*)lds + ABYT + dBt;
    const bool tail = (t < 128);

    // ---- fragment read offsets. Logical row base+llo (base mult of 16) ->
    // prow = base/2 + (llo>>1); prow&7 = (llo>>1)&7 (per-lane const).
    // klo < 128, row bases multiples of 128 -> no carry (R6 lesson).
    const unsigned klo = (unsigned)(((llo & 1) << 6) | (lhi << 4))
                       ^ (unsigned)(((llo >> 1) & 7) << 4);
    const unsigned laneR = (unsigned)((llo >> 1) * 128);
    const unsigned baseA = (unsigned)(wr * 4096) + laneR;              // + m*1024
    const unsigned baseB = (unsigned)ABYT + (unsigned)(wc * 5120) + laneR; // + n*1024

    f32x4 acc[4][5];
    #pragma unroll
    for (int m = 0; m < 4; ++m)
        #pragma unroll
        for (int n = 0; n < 5; ++n)
            acc[m][n] = f32x4{0.f, 0.f, 0.f, 0.f};

    // ---- prologue: stage T0 -> buf0
    gload_lds16(asrc0,          adst0);
    gload_lds16(asrc0 + 262144, adst0 + 8192);
    gload_lds16(bsrc0,          bdst0);
    if (tail) gload_lds16(bsrct, bdstt);
    asm volatile("s_waitcnt vmcnt(0)" ::: "memory");
    __builtin_amdgcn_s_barrier();

    for (int k = 0; k < NT; ++k) {
        const char* buf  = lds + (k & 1) * BUFSZ;
        const unsigned nb = (unsigned)(((k + 1) & 1) * BUFSZ);
        const int   koff = (k + 1) * 64;   // 32 bf16 per K-tile = 64 B

        // ---- early issue: stage tile k+1 (a full tile of latency cover)
        if (k + 1 < NT) {
            gload_lds16(asrc0 + koff,          adst0 + nb);
            gload_lds16(asrc0 + koff + 262144, adst0 + nb + 8192);
            gload_lds16(bsrc0 + koff,          bdst0 + nb);
            if (tail) gload_lds16(bsrct + koff, bdstt + nb);
        }

        // ---- compute: 9 ds_read_b128 + 20 MFMA, compiler-scheduled
        bf16x8 af[4], bfr[5];
        #pragma unroll
        for (int m = 0; m < 4; ++m)
            af[m]  = *(const bf16x8*)(buf + baseA + m * 1024 + klo);
        #pragma unroll
        for (int n = 0; n < 5; ++n)
            bfr[n] = *(const bf16x8*)(buf + baseB + n * 1024 + klo);
        #pragma unroll
        for (int m = 0; m < 4; ++m)
            #pragma unroll
            for (int n = 0; n < 5; ++n)
                acc[m][n] = __builtin_amdgcn_mfma_f32_16x16x32_bf16(
                    af[m], bfr[n], acc[m][n], 0, 0, 0);

        // ---- tile boundary: staged loads had a full tile to land
        asm volatile("s_waitcnt vmcnt(0)" ::: "memory");
        __builtin_amdgcn_s_barrier();
    }

    // ---- epilogue: bias + sigmoid; C/D: col = lane&15, row = (lane>>4)*4+reg
    #pragma unroll
    for (int n = 0; n < 5; ++n) {
        const int col  = bn0 + wc * 80 + n * 16 + llo;
        const float bv = bias[col];
        #pragma unroll
        for (int m = 0; m < 4; ++m) {
            const int row0 = bm0 + wr * 64 + m * 16 + lhi * 4;
            #pragma unroll
            for (int r = 0; r < 4; ++r) {
                const float z = acc[m][n][r] + bv;
                out[(size_t)(row0 + r) * HEADS + col] = __fdividef(1.0f, 1.0f + __expf(-z));
            }
        }
    }
}

// ---------------------------------------------------------------------------
// Fallback (R1 fused kernel) if workspace is too small.
// ---------------------------------------------------------------------------
#define FBM 128
#define FBN 128
#define FBK 32
#define FLDK 40

__global__ __launch_bounds__(256)
void lch_gemm(const float* __restrict__ x, const float* __restrict__ W,
              const float* __restrict__ b, float* __restrict__ out)
{
    __shared__ __bf16 As[FBM][FLDK];
    __shared__ __bf16 Bs[FBN][FLDK];

    const int t   = threadIdx.x;
    const int bm0 = blockIdx.x * FBM;
    const int bn0 = blockIdx.y * FBN;
    const int lane = t & 63;
    const int wid  = t >> 6;
    const int wr   = wid >> 1;
    const int wc   = wid & 1;
    const int lhi  = lane >> 4;
    const int llo  = lane & 15;

    f32x4 acc[4][4];
    #pragma unroll
    for (int i = 0; i < 4; ++i)
        #pragma unroll
        for (int j = 0; j < 4; ++j)
            acc[i][j] = f32x4{0.f, 0.f, 0.f, 0.f};

    const int bn_col  = t & 127;
    const int bk_base = (t >> 7) * 16;

    for (int k0 = 0; k0 < HIDDEN; k0 += FBK) {
        #pragma unroll
        for (int i = 0; i < 4; ++i) {
            const int f   = t + i * 256;
            const int row = f >> 3;
            const int c4  = (f & 7) * 4;
            const float4 v = *reinterpret_cast<const float4*>(
                x + (size_t)(bm0 + row) * HIDDEN + k0 + c4);
            bf16x4 h;
            h[0] = (__bf16)v.x; h[1] = (__bf16)v.y;
            h[2] = (__bf16)v.z; h[3] = (__bf16)v.w;
            *reinterpret_cast<bf16x4*>(&As[row][c4]) = h;
        }
        {
            const float* wp = W + (size_t)(k0 + bk_base) * HEADS + bn0 + bn_col;
            bf16x8 h0, h1;
            #pragma unroll
            for (int i = 0; i < 8; ++i) h0[i] = (__bf16)wp[(size_t)i * HEADS];
            #pragma unroll
            for (int i = 0; i < 8; ++i) h1[i] = (__bf16)wp[(size_t)(i + 8) * HEADS];
            *reinterpret_cast<bf16x8*>(&Bs[bn_col][bk_base])     = h0;
            *reinterpret_cast<bf16x8*>(&Bs[bn_col][bk_base + 8]) = h1;
        }
        __syncthreads();

        bf16x8 af[4], bfr[4];
        #pragma unroll
        for (int i = 0; i < 4; ++i)
            af[i] = *reinterpret_cast<const bf16x8*>(&As[wr * 64 + i * 16 + llo][lhi * 8]);
        #pragma unroll
        for (int j = 0; j < 4; ++j)
            bfr[j] = *reinterpret_cast<const bf16x8*>(&Bs[wc * 64 + j * 16 + llo][lhi * 8]);
        #pragma unroll
        for (int i = 0; i < 4; ++i)
            #pragma unroll
            for (int j = 0; j < 4; ++j)
                acc[i][j] = __builtin_amdgcn_mfma_f32_16x16x32_bf16(
                    af[i], bfr[j], acc[i][j], 0, 0, 0);
        __syncthreads();
    }

    #pragma unroll
    for (int j = 0; j < 4; ++j) {
        const int col  = bn0 + wc * 64 + j * 16 + llo;
        const float bv = b[col];
        #pragma unroll
        for (int i = 0; i < 4; ++i) {
            const int row0 = bm0 + wr * 64 + i * 16 + lhi * 4;
            #pragma unroll
            for (int r = 0; r < 4; ++r) {
                const float z = acc[i][j][r] + bv;
                out[(size_t)(row0 + r) * HEADS + col] = 1.0f / (1.0f + __expf(-z));
            }
        }
    }
}

extern "C" void kernel_launch(void* const* d_in, const int* in_sizes, int n_in,
                              void* d_out, int out_size, void* d_ws, size_t ws_size,
                              hipStream_t stream) {
    const float* x = (const float*)d_in[0];
    const float* W = (const float*)d_in[1];
    const float* b = (const float*)d_in[2];
    float* out     = (float*)d_out;

    const int M = in_sizes[0] / HIDDEN;   // 8192

    const size_t xc_bytes = (size_t)M * HIDDEN * sizeof(__bf16);
    const size_t wt_bytes = (size_t)HEADS * HIDDEN * sizeof(__bf16);

    if (ws_size >= xc_bytes + wt_bytes && (M % BM) == 0) {
        __bf16* xc = (__bf16*)d_ws;
        __bf16* Wt = (__bf16*)((char*)d_ws + xc_bytes);

        cvt_all<<<640 + 2048, 256, 0, stream>>>(x, W, xc, Wt, M * HIDDEN / 8);

        const int nwg = (M / BM) * (HEADS / BN);   // 32 * 16 = 512
        gemm_pp<<<nwg, 512, 0, stream>>>(xc, Wt, b, out);
    } else {
        dim3 grid(M / FBM, HEADS / FBN);
        lch_gemm<<<grid, dim3(256), 0, stream>>>(x, W, b, out);
    }
}